// Round 3
// baseline (187.435 us; speedup 1.0000x reference)
//
#include <hip/hip_runtime.h>
#include <hip/hip_bf16.h>

typedef unsigned int uint32;
typedef unsigned long long uint64;
typedef unsigned short ushort_t;

#define KNEI 32
#define DIM 128
#define ROW_BYTES 272                      // 256 B bf16 row + 16 B pad (68 dwords ≡ 4 mod 32 banks)
#define WAVE_LDS (KNEI * ROW_BYTES)        // 8704 B per wave
#define WPB 4                              // waves per block

__device__ __forceinline__ float bflo(uint32 u) {
    union { uint32 u; float f; } c; c.u = u << 16; return c.f;
}
__device__ __forceinline__ float bfhi(uint32 u) {
    union { uint32 u; float f; } c; c.u = u & 0xffff0000u; return c.f;
}
__device__ __forceinline__ uint32 pack_bf16_rne(float a, float b) {
    union { float f; uint32 u; } x, y; x.f = a; y.f = b;
    uint32 ua = (x.u + 0x7fffu + ((x.u >> 16) & 1u)) >> 16;
    uint32 ub = (y.u + 0x7fffu + ((y.u >> 16) & 1u)) >> 16;
    return (ua & 0xffffu) | (ub << 16);
}

// F32 = float tensors (h, h_refer, att, out) are float32; otherwise bf16.
// i64 = nei is int64. All branches are wave-uniform.
template<bool F32>
__device__ __forceinline__ void run_row(
    const void* __restrict__ hv, const void* __restrict__ hrv,
    const void* __restrict__ attv, void* __restrict__ outv,
    const void* __restrict__ neiv, bool i64, int Mrows,
    char* wbase, int n, int lane)
{
    const int l  = lane & 31;              // k index for score phase
    const int hf = lane >> 5;              // half-dim selector

    int idxv;
    if (i64) idxv = (int)((const long long*)neiv)[(size_t)n * KNEI + l];
    else     idxv = ((const int*)neiv)[(size_t)n * KNEI + l];
    idxv = min(max(idxv, 0), Mrows - 1);   // OOB armor

    // Phase 1: stage 32 neighbor rows into LDS as bf16 (256 B/row, stride 272).
    // lane covers row r = it*4 + (lane>>4), 8-dim chunk c = lane&15.
    {
        const int r4 = lane >> 4;
        const int c  = lane & 15;
        #pragma unroll
        for (int it = 0; it < 8; ++it) {
            const int r   = it * 4 + r4;
            const int row = __shfl(idxv, r, 64);
            uint4 st;
            if (F32) {
                const float4* src = (const float4*)((const float*)hv + (size_t)row * DIM + c * 8);
                const float4 p0 = src[0], p1 = src[1];
                st.x = pack_bf16_rne(p0.x, p0.y);
                st.y = pack_bf16_rne(p0.z, p0.w);
                st.z = pack_bf16_rne(p1.x, p1.y);
                st.w = pack_bf16_rne(p1.z, p1.w);
            } else {
                st = *((const uint4*)((const ushort_t*)hv + (size_t)row * DIM) + c);
            }
            *(uint4*)(wbase + r * ROW_BYTES + c * 16) = st;
        }
    }

    // Phase 1.5: base = dot(h_refer[n], att_ref); lane holds dims 2*lane, 2*lane+1
    float b0, b1, a0, a1;
    if (F32) {
        const float2 hp = *((const float2*)((const float*)hrv + (size_t)n * DIM) + lane);
        const float2 ap = *((const float2*)attv + lane);
        b0 = hp.x; b1 = hp.y; a0 = ap.x; a1 = ap.y;
    } else {
        const uint32 hu = ((const uint32*)((const ushort_t*)hrv + (size_t)n * DIM))[lane];
        const uint32 au = ((const uint32*)attv)[lane];
        b0 = bflo(hu); b1 = bfhi(hu); a0 = bflo(au); a1 = bfhi(au);
    }
    float base = b0 * a0 + b1 * a1;
    #pragma unroll
    for (int off = 32; off >= 1; off >>= 1)
        base += __shfl_xor(base, off, 64);

    __syncthreads();

    // Phase 2: score_l = base + dot(row_l, att_nei); lane (l,hf) covers dims [64*hf, 64*hf+64)
    float part = 0.f;
    #pragma unroll
    for (int j = 0; j < 8; ++j) {
        const uint4 ev = *(const uint4*)(wbase + l * ROW_BYTES + hf * 128 + j * 16);
        float v0, v1, v2, v3, v4, v5, v6, v7;
        if (F32) {
            const float4* ap = (const float4*)((const float*)attv + DIM + hf * 64 + j * 8);
            const float4 p0 = ap[0], p1 = ap[1];
            v0 = p0.x; v1 = p0.y; v2 = p0.z; v3 = p0.w;
            v4 = p1.x; v5 = p1.y; v6 = p1.z; v7 = p1.w;
        } else {
            const uint4 au = *((const uint4*)((const ushort_t*)attv + DIM + hf * 64) + j);
            v0 = bflo(au.x); v1 = bfhi(au.x); v2 = bflo(au.y); v3 = bfhi(au.y);
            v4 = bflo(au.z); v5 = bfhi(au.z); v6 = bflo(au.w); v7 = bfhi(au.w);
        }
        part += bflo(ev.x) * v0 + bfhi(ev.x) * v1 + bflo(ev.y) * v2 + bfhi(ev.y) * v3
              + bflo(ev.z) * v4 + bfhi(ev.z) * v5 + bflo(ev.w) * v6 + bfhi(ev.w) * v7;
    }
    part += __shfl_xor(part, 32, 64);      // combine half-dim partials
    float s = base + part;
    s = (s > 0.f) ? s : 0.01f * s;         // leaky_relu

    // softmax over the 32 k-values (duplicated across halves)
    float m = s;
    #pragma unroll
    for (int off = 16; off >= 1; off >>= 1)
        m = fmaxf(m, __shfl_xor(m, off, 64));
    const float ex = __expf(s - m);
    float sum = ex;
    #pragma unroll
    for (int off = 16; off >= 1; off >>= 1)
        sum += __shfl_xor(sum, off, 64);
    const float w = ex / sum;              // lane (k, hf) holds w_k

    // Phase 3: out[n][d] = sum_k w_k * row_k[d]; lane covers d = 2*lane, 2*lane+1
    // bank = (68k + lane) % 32 = (4k + lane) % 32 -> conflict-free per k.
    float acc0 = 0.f, acc1 = 0.f;
    #pragma unroll
    for (int k = 0; k < KNEI; ++k) {
        const float wk = __shfl(w, k, 64);
        const uint32 ev = *(const uint32*)(wbase + k * ROW_BYTES + lane * 4);
        acc0 = fmaf(wk, bflo(ev), acc0);
        acc1 = fmaf(wk, bfhi(ev), acc1);
    }
    if (F32) {
        float2 o; o.x = acc0; o.y = acc1;
        *((float2*)((float*)outv + (size_t)n * DIM) + lane) = o;
    } else {
        ((uint32*)((ushort_t*)outv + (size_t)n * DIM))[lane] = pack_bf16_rne(acc0, acc1);
    }
}

__global__ __launch_bounds__(256) void gat_kernel(
    const void* __restrict__ nei, const void* __restrict__ h,
    const void* __restrict__ h_refer, const void* __restrict__ att,
    void* __restrict__ out, int N, int Mrows)
{
    __shared__ __align__(16) char smem[WPB * WAVE_LDS];
    const int tid  = threadIdx.x;
    const int wave = tid >> 6;
    const int lane = tid & 63;
    const int n    = blockIdx.x * WPB + wave;

    // ---- dtype probes (all 64 lanes active; wave-uniform results) ----
    // h: bf16 iff bits 14..7 of every sampled dword look like a bf16 exponent.
    const uint32 hs = ((const uint32*)h)[lane];
    const uint32 e  = (hs >> 7) & 0xFFu;
    const bool  tb  = (e >= 90u) && (e <= 140u);
    const bool is_bf16 = (__ballot(tb) == ~0ull);
    // nei: int64 iff all odd dwords in the first 128 are zero.
    const uint32 nhi = ((const uint32*)nei)[2 * lane + 1];
    const bool  i64  = (__ballot(nhi == 0u) == ~0ull);

    char* wbase = smem + wave * WAVE_LDS;

    if (n < N) {
        if (is_bf16) run_row<false>(h, h_refer, att, out, nei, i64, Mrows, wbase, n, lane);
        else         run_row<true >(h, h_refer, att, out, nei, i64, Mrows, wbase, n, lane);
    } else {
        __syncthreads();
    }
}

extern "C" void kernel_launch(void* const* d_in, const int* in_sizes, int n_in,
                              void* d_out, int out_size, void* d_ws, size_t ws_size,
                              hipStream_t stream) {
    const int N = out_size / DIM;          // authoritative: output rows
    const int M = in_sizes[1] / DIM;       // h rows (element count is dtype-independent)

    dim3 grid((N + WPB - 1) / WPB), block(64 * WPB);
    gat_kernel<<<grid, block, 0, stream>>>(d_in[0], d_in[1], d_in[2], d_in[3],
                                           d_out, N, M);
}